// Round 7
// baseline (355.420 us; speedup 1.0000x reference)
//
#include <hip/hip_runtime.h>

// Multires hash-grid encode (2D, instant-NGP style). Round 10: DIRECT-WRITE.
//
// Consolidated evidence:
//  - XCD table affinity (level-major, one hashed table per XCD) is the only
//    regime where hashed gathers hit L2: pass 1 = 131 us (round 4). Without
//    it every fused variant pays ~670 MiB L2-miss line traffic at the
//    ~3.7 TB/s fabric ceiling = 210-230 us (rounds 7/9).
//  - Pass 1 is divergent-request-rate bound (2x MLP: no effect; VALU 10%,
//    HBM 18%, occ 76% -> all pipes idle).
//  - The transpose pass (~90 us) + 128-MiB ws round-trip exist ONLY to
//    convert level-major to point-major. Round-9 also showed scattered
//    direct stores amplify WRITE ~2.6x but still complete.
//
// This round: keep round-4 pass 1 VERBATIM (known 131 us), but store each
// (point, level) result directly to its final 8-B slice out[n][l] with a
// non-temporal store. No ws, no pass 2, one launch. nt = write-through with
// byte masks: no L2 allocation (table residency undisturbed); partial
// 64-B chunks from different XCDs merge in the memory-side Infinity Cache.
// Cost: +8M uncoalesced store requests (~+25 us on the request-rate model)
// and write amplification; benefit: -90 us pass + -128 MiB ws traffic.
// Index math bit-exact vs the jax reference (32-bit residue proof below).

static constexpr int  kPoints    = 524288;
static constexpr int  kLevels    = 16;
static constexpr int  kStartHash = 6;
static constexpr unsigned kPs1     = 19349663u;
static constexpr unsigned kEntries = 524309u;
static constexpr unsigned kR32     = 352277u;   // 2^32 mod kEntries

typedef float v2f __attribute__((ext_vector_type(2)));

__device__ __forceinline__ void nt_store2(float2* p, const float2 v) {
    v2f t; t.x = v.x; t.y = v.y;
    __builtin_nontemporal_store(t, (v2f*)p);
}

__constant__ unsigned c_level_off[kLevels] = {
    0u, 289u, 1378u, 5603u, 22244u, 88293u, 351462u,
    875771u, 1400080u, 1924389u, 2448698u, 2973007u,
    3497316u, 4021625u, 4545934u, 5070243u
};

struct Corners {
    float    w00, w01, w10, w11;
    unsigned i00, i01, i10, i11;   // absolute table indices (level base folded in)
};

__device__ __forceinline__ Corners prep_level(const float2 p, const int l)
{
    const int   scale_i = 16 << l;
    const float scale_f = (float)scale_i;

    const float fx = p.x * scale_f;
    const float fy = p.y * scale_f;

    // coords in [0,1) -> indices nonnegative, max 524288 at level 15: u32 ok.
    const unsigned ix0 = (unsigned)(int)fx;
    const unsigned iy0 = (unsigned)(int)fy;
    const unsigned ix1 = (unsigned)(int)(fx + 1.0f);   // NOT always ix0+1 (fp rounding)
    const unsigned iy1 = (unsigned)(int)(fy + 1.0f);

    const float ox = fx - (float)ix0;
    const float oy = fy - (float)iy0;

    const float wx1 = fminf(fmaxf(ox, 0.0f), 1.0f);
    const float wx0 = fminf(fmaxf(1.0f - ox, 0.0f), 1.0f);
    const float wy1 = fminf(fmaxf(oy, 0.0f), 1.0f);
    const float wy0 = fminf(fmaxf(1.0f - oy, 0.0f), 1.0f);

    unsigned i00, i01, i10, i11;
    if (l < kStartHash) {
        const unsigned stride = (unsigned)(scale_i + 1);
        i00 = ix0 * stride + iy0;
        i01 = ix0 * stride + iy1;
        i10 = ix1 * stride + iy0;
        i11 = ix1 * stride + iy1;
    } else {
        // 32-bit replication of ((ix ^ (iy*PS1)) % E), bit-exact vs int64:
        // hy = iy*PS1 = hi*2^32+lo, hi <= 2362, ix < 2^20 so xor touches lo only.
        // (hi*2^32 + (lo^ix)) % E = ((hi*R32)%E + (lo^ix)%E) cond-sub E.
        const unsigned long long hy0 = (unsigned long long)iy0 * kPs1;
        const unsigned long long hy1 = (unsigned long long)iy1 * kPs1;
        const unsigned lo0 = (unsigned)hy0, hi0 = (unsigned)(hy0 >> 32);
        const unsigned lo1 = (unsigned)hy1, hi1 = (unsigned)(hy1 >> 32);
        const unsigned a0 = (hi0 * kR32) % kEntries;   // hi*R32 < 2^30
        const unsigned a1 = (hi1 * kR32) % kEntries;
        i00 = a0 + ((lo0 ^ ix0) % kEntries); if (i00 >= kEntries) i00 -= kEntries;
        i01 = a1 + ((lo1 ^ ix0) % kEntries); if (i01 >= kEntries) i01 -= kEntries;
        i10 = a0 + ((lo0 ^ ix1) % kEntries); if (i10 >= kEntries) i10 -= kEntries;
        i11 = a1 + ((lo1 ^ ix1) % kEntries); if (i11 >= kEntries) i11 -= kEntries;
    }

    Corners c;
    const unsigned base = c_level_off[l];
    c.i00 = base + i00; c.i01 = base + i01;
    c.i10 = base + i10; c.i11 = base + i11;
    c.w00 = wx0 * wy0;  c.w01 = wx0 * wy1;
    c.w10 = wx1 * wy0;  c.w11 = wx1 * wy1;
    return c;
}

__device__ __forceinline__ float2 finish_level(
    const Corners& c, const float2* __restrict__ tbl)
{
    const float2 v00 = tbl[c.i00];
    const float2 v01 = tbl[c.i01];
    const float2 v10 = tbl[c.i10];
    const float2 v11 = tbl[c.i11];
    return make_float2(
        c.w00 * v00.x + c.w01 * v01.x + c.w10 * v10.x + c.w11 * v11.x,
        c.w00 * v00.y + c.w01 * v01.y + c.w10 * v10.y + c.w11 * v11.y);
}

// ---- Single pass: XCD-partitioned level-major gather, direct nt writes --
// out viewed as float2[N][16]: level l of point n lives at out2[n*16 + l].
__global__ __launch_bounds__(256) void level_pass(
    const float2* __restrict__ x,
    const float2* __restrict__ tbl,
    float2* __restrict__ out2)
{
    const int b    = blockIdx.x;
    const int xcd  = b & 7;         // blockIdx%8 round-robins the 8 XCDs
    const int slot = b >> 3;        // 0..4095

    int level, pblk;
    if (slot < 2048) {
        level = 6 + xcd;            // hashed levels 6..13, one table per XCD
        pblk  = slot;
    } else if (slot < 2304) {
        level = 14;                 // split 8 ways
        pblk  = xcd * 256 + (slot - 2048);
    } else if (slot < 2560) {
        level = 15;                 // split 8 ways
        pblk  = xcd * 256 + (slot - 2304);
    } else {
        const int d = xcd * 1536 + (slot - 2560);  // 0..12287
        level = d >> 11;            // dense levels 0..5
        pblk  = d & 2047;
    }

    const int n = (pblk << 8) | threadIdx.x;
    const float2 p = x[n];
    const float2 r = finish_level(prep_level(p, level), tbl);

    // Direct 8-B slice store. Scattered (stride 128 B across lanes), but:
    // nt write-through carries byte masks end-to-end, does not allocate in
    // L2 (table residency preserved), and partial chunks from different
    // XCDs merge in the memory-side Infinity Cache before HBM.
    nt_store2(&out2[(size_t)n * kLevels + level], r);
}

extern "C" void kernel_launch(void* const* d_in, const int* in_sizes, int n_in,
                              void* d_out, int out_size, void* d_ws, size_t ws_size,
                              hipStream_t stream) {
    const float2* x   = (const float2*)d_in[0];
    const float2* tbl = (const float2*)d_in[1];
    level_pass<<<kLevels * (kPoints / 256), 256, 0, stream>>>(
        x, tbl, (float2*)d_out);
}

// Round 8
// 211.834 us; speedup vs baseline: 1.6778x; 1.6778x over previous
//
#include <hip/hip_runtime.h>

// Multires hash-grid encode (2D, instant-NGP style). Round 11: PAIRED LOADS.
//
// Locked-in structure (rounds 4-10 evidence):
//  - Two passes. XCD table affinity in pass 1 is mandatory (fused variants
//    pay ~670 MiB L2-miss fabric traffic = 210-280 us). Output must leave
//    via coalesced float4 stores (direct scattered stores = 4x write amp).
//  - Pass 1 is gather-REQUEST-throughput bound: 33.5M divergent lane
//    requests / 314K cy ~ 13.3 req/cy/XCD-L2 (~83% of 16/cy). Not VALU
//    (10%), not latency (2x MLP null), not occupancy (76%).
// This round attacks request count + pass-2 parallelism:
//  (a) Corner pairs that land on adjacent table entries (dense: i01==i00+1
//      always; hashed: i10==i00+1 when ix0 even — xor flips only bit 0)
//      with an even base are loaded as ONE aligned 16-B dwordx4 instead of
//      two 8-B dwordx2 -> ~17% fewer requests. Adjacency is TESTED per-lane
//      on the exact final indices, never assumed -> bit-exact always.
//  (b) Pass 2: 64-point tiles (grid 8192, 4x blocks/CU vs round 4), LDS
//      stride 66 float2 (max 2-way bank aliasing = free on CDNA4).
//  Reverted round-3 regressions: 1 pt/thread, plain (cached) ws stores.

static constexpr int  kPoints    = 524288;
static constexpr int  kLevels    = 16;
static constexpr int  kStartHash = 6;
static constexpr unsigned kPs1     = 19349663u;
static constexpr unsigned kEntries = 524309u;
static constexpr unsigned kR32     = 352277u;   // 2^32 mod kEntries

typedef float v4f __attribute__((ext_vector_type(4)));

__device__ __forceinline__ void nt_store4(float4* p, const float4 v) {
    v4f t; t.x = v.x; t.y = v.y; t.z = v.z; t.w = v.w;
    __builtin_nontemporal_store(t, (v4f*)p);
}

__constant__ unsigned c_level_off[kLevels] = {
    0u, 289u, 1378u, 5603u, 22244u, 88293u, 351462u,
    875771u, 1400080u, 1924389u, 2448698u, 2973007u,
    3497316u, 4021625u, 4545934u, 5070243u
};

struct Corners {
    float    w00, w01, w10, w11;
    unsigned i00, i01, i10, i11;   // absolute table indices (level base folded in)
};

__device__ __forceinline__ Corners prep_level(const float2 p, const int l)
{
    const int   scale_i = 16 << l;
    const float scale_f = (float)scale_i;

    const float fx = p.x * scale_f;
    const float fy = p.y * scale_f;

    // coords in [0,1) -> indices nonnegative, max ~524289 at level 15: u32 ok.
    const unsigned ix0 = (unsigned)(int)fx;
    const unsigned iy0 = (unsigned)(int)fy;
    const unsigned ix1 = (unsigned)(int)(fx + 1.0f);   // NOT always ix0+1 (fp rounding)
    const unsigned iy1 = (unsigned)(int)(fy + 1.0f);

    const float ox = fx - (float)ix0;
    const float oy = fy - (float)iy0;

    const float wx1 = fminf(fmaxf(ox, 0.0f), 1.0f);
    const float wx0 = fminf(fmaxf(1.0f - ox, 0.0f), 1.0f);
    const float wy1 = fminf(fmaxf(oy, 0.0f), 1.0f);
    const float wy0 = fminf(fmaxf(1.0f - oy, 0.0f), 1.0f);

    unsigned i00, i01, i10, i11;
    if (l < kStartHash) {
        const unsigned stride = (unsigned)(scale_i + 1);
        i00 = ix0 * stride + iy0;
        i01 = ix0 * stride + iy1;
        i10 = ix1 * stride + iy0;
        i11 = ix1 * stride + iy1;
    } else {
        // 32-bit replication of ((ix ^ (iy*PS1)) % E), bit-exact vs int64:
        // hy = iy*PS1 = hi*2^32+lo, hi <= 2362, ix < 2^20 so xor touches lo only.
        // (hi*2^32 + (lo^ix)) % E = ((hi*R32)%E + (lo^ix)%E) cond-sub E.
        const unsigned long long hy0 = (unsigned long long)iy0 * kPs1;
        const unsigned long long hy1 = (unsigned long long)iy1 * kPs1;
        const unsigned lo0 = (unsigned)hy0, hi0 = (unsigned)(hy0 >> 32);
        const unsigned lo1 = (unsigned)hy1, hi1 = (unsigned)(hy1 >> 32);
        const unsigned a0 = (hi0 * kR32) % kEntries;   // hi*R32 < 2^30
        const unsigned a1 = (hi1 * kR32) % kEntries;
        i00 = a0 + ((lo0 ^ ix0) % kEntries); if (i00 >= kEntries) i00 -= kEntries;
        i01 = a1 + ((lo1 ^ ix0) % kEntries); if (i01 >= kEntries) i01 -= kEntries;
        i10 = a0 + ((lo0 ^ ix1) % kEntries); if (i10 >= kEntries) i10 -= kEntries;
        i11 = a1 + ((lo1 ^ ix1) % kEntries); if (i11 >= kEntries) i11 -= kEntries;
    }

    Corners c;
    const unsigned base = c_level_off[l];
    c.i00 = base + i00; c.i01 = base + i01;
    c.i10 = base + i10; c.i11 = base + i11;
    c.w00 = wx0 * wy0;  c.w01 = wx0 * wy1;
    c.w10 = wx1 * wy0;  c.w11 = wx1 * wy1;
    return c;
}

// Load tbl[ia] and tbl[ib]. When they are adjacent with even base, one
// aligned 16-B load serves both (1 TA/L2 request instead of 2). The
// condition is TESTED on the exact indices -> result always bit-exact.
__device__ __forceinline__ void load_pair(
    const float2* __restrict__ tbl, const unsigned ia, const unsigned ib,
    float2& va, float2& vb)
{
    if (ib == ia + 1u && !(ia & 1u)) {
        const v4f q = *reinterpret_cast<const v4f*>(&tbl[ia]);  // 16-B aligned
        va = make_float2(q.x, q.y);
        vb = make_float2(q.z, q.w);
    } else {
        va = tbl[ia];
        vb = tbl[ib];
    }
}

// ---- Pass 1: XCD-partitioned level-major gather, paired loads -----------
__global__ __launch_bounds__(256) void level_pass(
    const float2* __restrict__ x,
    const float2* __restrict__ tbl,
    float2* __restrict__ ws)
{
    const int b    = blockIdx.x;
    const int xcd  = b & 7;         // blockIdx%8 round-robins the 8 XCDs
    const int slot = b >> 3;        // 0..4095

    int level, pblk;
    if (slot < 2048) {
        level = 6 + xcd;            // hashed levels 6..13, one table per XCD
        pblk  = slot;
    } else if (slot < 2304) {
        level = 14;                 // split 8 ways
        pblk  = xcd * 256 + (slot - 2048);
    } else if (slot < 2560) {
        level = 15;                 // split 8 ways
        pblk  = xcd * 256 + (slot - 2304);
    } else {
        const int d = xcd * 1536 + (slot - 2560);  // 0..12287
        level = d >> 11;            // dense levels 0..5
        pblk  = d & 2047;
    }

    const int n = (pblk << 8) | threadIdx.x;
    const float2 p = x[n];
    const Corners c = prep_level(p, level);

    float2 v00, v01, v10, v11;
    if (level < kStartHash) {
        // dense: y-neighbors are adjacent entries (i01 == i00+1 always)
        load_pair(tbl, c.i00, c.i01, v00, v01);
        load_pair(tbl, c.i10, c.i11, v10, v11);
    } else {
        // hashed: xor flips only bit 0 when ix0 even -> x-neighbors adjacent
        load_pair(tbl, c.i00, c.i10, v00, v10);
        load_pair(tbl, c.i01, c.i11, v01, v11);
    }

    const float2 r = make_float2(
        c.w00 * v00.x + c.w01 * v01.x + c.w10 * v10.x + c.w11 * v11.x,
        c.w00 * v00.y + c.w01 * v01.y + c.w10 * v10.y + c.w11 * v11.y);

    // tile-major ws[n>>8][16][256] float2, plain cached store (round-3
    // showed nt stores here were a mild regression).
    ws[((size_t)pblk << 12) + (level << 8) + threadIdx.x] = r;
}

// ---- Pass 2: 64-point LDS tiles, grid 8192 ------------------------------
static constexpr int kT2S = 66;     // LDS row stride in float2: 4*66 mod 32 = 8
                                    // -> max 2-way bank aliasing (free, m136)

__global__ __launch_bounds__(256) void transpose_out(
    const float2* __restrict__ ws,
    float4* __restrict__ out)
{
    __shared__ float2 lds[kLevels][kT2S];   // 8.4 KB

    const int t = threadIdx.x;
    const int b = blockIdx.x;               // 8192 tiles of 64 points
    const int chunk = b >> 2;               // 256-pt ws chunk
    const int coff  = (b & 3) << 6;         // 64-pt offset inside chunk
    const float2* __restrict__ base = ws + ((size_t)chunk << 12) + coff;

#pragma unroll
    for (int k = 0; k < 4; ++k) {
        const int e = (k << 8) + t;         // 0..1023 = 16 levels x 64 pts
        const int l = e >> 6;
        const int cc = e & 63;
        lds[l][cc] = base[(l << 8) + cc];   // coalesced 512-B runs per level
    }

    __syncthreads();

    float4* o = out + ((size_t)b << 9);     // 64 pts * 8 float4
#pragma unroll
    for (int k = 0; k < 2; ++k) {
        const int g  = (k << 8) + t;        // 0..511
        const int nl = g >> 3;              // local point
        const int i  = g & 7;               // float4 index in the 32-float row
        const float2 a  = lds[2 * i][nl];
        const float2 bb = lds[2 * i + 1][nl];
        nt_store4(&o[g], make_float4(a.x, a.y, bb.x, bb.y));
    }
}

// ---- Fallback: single-pass (if ws too small) ----------------------------
__global__ __launch_bounds__(256) void hashgrid_fwd(
    const float2* __restrict__ x,
    const float2* __restrict__ tbl,
    float4* __restrict__ out)
{
    const int n = blockIdx.x * blockDim.x + threadIdx.x;
    if (n >= kPoints) return;
    const float2 p = x[n];
    float acc[2 * kLevels];
#pragma unroll
    for (int l = 0; l < kLevels; ++l) {
        const Corners c = prep_level(p, l);
        const float2 v00 = tbl[c.i00], v01 = tbl[c.i01];
        const float2 v10 = tbl[c.i10], v11 = tbl[c.i11];
        acc[2 * l + 0] = c.w00 * v00.x + c.w01 * v01.x + c.w10 * v10.x + c.w11 * v11.x;
        acc[2 * l + 1] = c.w00 * v00.y + c.w01 * v01.y + c.w10 * v10.y + c.w11 * v11.y;
    }
    float4* o = out + (size_t)n * 8;
#pragma unroll
    for (int i = 0; i < 8; ++i)
        o[i] = make_float4(acc[4 * i + 0], acc[4 * i + 1],
                           acc[4 * i + 2], acc[4 * i + 3]);
}

extern "C" void kernel_launch(void* const* d_in, const int* in_sizes, int n_in,
                              void* d_out, int out_size, void* d_ws, size_t ws_size,
                              hipStream_t stream) {
    const float2* x   = (const float2*)d_in[0];
    const float2* tbl = (const float2*)d_in[1];

    const size_t ws_needed = (size_t)kLevels * kPoints * sizeof(float2); // 64 MiB
    if (ws_size >= ws_needed) {
        float2* ws = (float2*)d_ws;
        level_pass<<<kLevels * (kPoints / 256), 256, 0, stream>>>(x, tbl, ws);
        transpose_out<<<kPoints / 64, 256, 0, stream>>>(ws, (float4*)d_out);
    } else {
        hashgrid_fwd<<<kPoints / 256, 256, 0, stream>>>(x, tbl, (float4*)d_out);
    }
}

// Round 9
// 202.219 us; speedup vs baseline: 1.7576x; 1.0475x over previous
//
#include <hip/hip_runtime.h>

// Multires hash-grid encode (2D, instant-NGP style). Round 12: FULL PAIRING.
//
// Budget discovery (R7/R9 single-dispatch rounds): dur_us carries a ~75 us
// FIXED harness overhead (gap between kernel time and reported total).
// Real split of R11's 211.8: pass1=117, pass2~20 (== its 128-MiB BW floor),
// overhead~75. All remaining leverage is pass 1, which is gather-REQUEST-
// throughput bound (R11: -17% requests -> -11% dur, as predicted).
//
// This round cuts requests further:
//  (a) Pairing no longer requires an even base: gfx950 global dwordx4 needs
//      only dword alignment (8-B-aligned 16-B loads are legal; the ~1/8
//      64-B-line crossers cost the 2 requests we'd pay unpaired anyway).
//      Dense corner pairs (i01==i00+1 ALWAYS) now pair 100% -> 2 req/pt.
//  (b) Hashed levels: when ix0 is even the xor flips only bit 0, giving
//      i10 = i00 +/- 1. R11 only caught +1; testing BOTH orders doubles
//      hashed pairing to ~50% of pairs -> ~3 req/pt. Adjacency is tested
//      on exact final indices -> bit-exact, and every 16-B load spans two
//      valid entries (never OOB).
//  (c) x-dedup: levels 14+15 merged into one job, dense 0..5 merged into
//      one job (x read 10x instead of 16x, FETCH -24 MiB). Hashed 6..13
//      keep strict 1-level-per-XCD L2 affinity (mandatory per R7/R9/R10).
// Expected: ~22M lane-requests (-21%), pass1 117 -> ~95-105 us.

static constexpr int  kPoints    = 524288;
static constexpr int  kLevels    = 16;
static constexpr int  kStartHash = 6;
static constexpr unsigned kPs1     = 19349663u;
static constexpr unsigned kEntries = 524309u;
static constexpr unsigned kR32     = 352277u;   // 2^32 mod kEntries

typedef float v4f __attribute__((ext_vector_type(4)));

__device__ __forceinline__ void nt_store4(float4* p, const float4 v) {
    v4f t; t.x = v.x; t.y = v.y; t.z = v.z; t.w = v.w;
    __builtin_nontemporal_store(t, (v4f*)p);
}

__constant__ unsigned c_level_off[kLevels] = {
    0u, 289u, 1378u, 5603u, 22244u, 88293u, 351462u,
    875771u, 1400080u, 1924389u, 2448698u, 2973007u,
    3497316u, 4021625u, 4545934u, 5070243u
};

struct Corners {
    float    w00, w01, w10, w11;
    unsigned i00, i01, i10, i11;   // absolute table indices (level base folded in)
};

__device__ __forceinline__ Corners prep_level(const float2 p, const int l)
{
    const int   scale_i = 16 << l;
    const float scale_f = (float)scale_i;

    const float fx = p.x * scale_f;
    const float fy = p.y * scale_f;

    // coords in [0,1) -> indices nonnegative, max ~524289 at level 15: u32 ok.
    const unsigned ix0 = (unsigned)(int)fx;
    const unsigned iy0 = (unsigned)(int)fy;
    const unsigned ix1 = (unsigned)(int)(fx + 1.0f);   // NOT always ix0+1 (fp rounding)
    const unsigned iy1 = (unsigned)(int)(fy + 1.0f);

    const float ox = fx - (float)ix0;
    const float oy = fy - (float)iy0;

    const float wx1 = fminf(fmaxf(ox, 0.0f), 1.0f);
    const float wx0 = fminf(fmaxf(1.0f - ox, 0.0f), 1.0f);
    const float wy1 = fminf(fmaxf(oy, 0.0f), 1.0f);
    const float wy0 = fminf(fmaxf(1.0f - oy, 0.0f), 1.0f);

    unsigned i00, i01, i10, i11;
    if (l < kStartHash) {
        const unsigned stride = (unsigned)(scale_i + 1);
        i00 = ix0 * stride + iy0;
        i01 = ix0 * stride + iy1;
        i10 = ix1 * stride + iy0;
        i11 = ix1 * stride + iy1;
    } else {
        // 32-bit replication of ((ix ^ (iy*PS1)) % E), bit-exact vs int64:
        // hy = iy*PS1 = hi*2^32+lo, hi <= 2362, ix < 2^20 so xor touches lo only.
        // (hi*2^32 + (lo^ix)) % E = ((hi*R32)%E + (lo^ix)%E) cond-sub E.
        const unsigned long long hy0 = (unsigned long long)iy0 * kPs1;
        const unsigned long long hy1 = (unsigned long long)iy1 * kPs1;
        const unsigned lo0 = (unsigned)hy0, hi0 = (unsigned)(hy0 >> 32);
        const unsigned lo1 = (unsigned)hy1, hi1 = (unsigned)(hy1 >> 32);
        const unsigned a0 = (hi0 * kR32) % kEntries;   // hi*R32 < 2^30
        const unsigned a1 = (hi1 * kR32) % kEntries;
        i00 = a0 + ((lo0 ^ ix0) % kEntries); if (i00 >= kEntries) i00 -= kEntries;
        i01 = a1 + ((lo1 ^ ix0) % kEntries); if (i01 >= kEntries) i01 -= kEntries;
        i10 = a0 + ((lo0 ^ ix1) % kEntries); if (i10 >= kEntries) i10 -= kEntries;
        i11 = a1 + ((lo1 ^ ix1) % kEntries); if (i11 >= kEntries) i11 -= kEntries;
    }

    Corners c;
    const unsigned base = c_level_off[l];
    c.i00 = base + i00; c.i01 = base + i01;
    c.i10 = base + i10; c.i11 = base + i11;
    c.w00 = wx0 * wy0;  c.w01 = wx0 * wy1;
    c.w10 = wx1 * wy0;  c.w11 = wx1 * wy1;
    return c;
}

// Load tbl[ia], tbl[ib]. If adjacent (either order), one 16-B load at the
// lower index serves both (8-B alignment is legal for dwordx4 on gfx950;
// the load always covers two VALID entries because both indices are valid).
__device__ __forceinline__ void load_pair(
    const float2* __restrict__ tbl, const unsigned ia, const unsigned ib,
    float2& va, float2& vb)
{
    if (ib == ia + 1u) {
        v4f q; __builtin_memcpy(&q, &tbl[ia], 16);
        va = make_float2(q.x, q.y);
        vb = make_float2(q.z, q.w);
    } else if (ia == ib + 1u) {
        v4f q; __builtin_memcpy(&q, &tbl[ib], 16);
        vb = make_float2(q.x, q.y);
        va = make_float2(q.z, q.w);
    } else {
        va = tbl[ia];
        vb = tbl[ib];
    }
}

__device__ __forceinline__ float2 gather_level(
    const float2* __restrict__ tbl, const Corners& c, const bool hashed)
{
    float2 v00, v01, v10, v11;
    if (!hashed) {
        // dense: y-neighbors adjacent ALWAYS (i01 == i00+1) -> 100% pairing
        load_pair(tbl, c.i00, c.i01, v00, v01);
        load_pair(tbl, c.i10, c.i11, v10, v11);
    } else {
        // hashed: ix0 even -> xor flips bit 0 -> i10 = i00 +/- 1 (~50%)
        load_pair(tbl, c.i00, c.i10, v00, v10);
        load_pair(tbl, c.i01, c.i11, v01, v11);
    }
    return make_float2(
        c.w00 * v00.x + c.w01 * v01.x + c.w10 * v10.x + c.w11 * v11.x,
        c.w00 * v00.y + c.w01 * v01.y + c.w10 * v10.y + c.w11 * v11.y);
}

// ---- Pass 1: XCD-affine hashed levels + merged dense/top jobs -----------
// Grid: 2560 slots x 8 XCDs = 20480 blocks.
//   slot    0..2047 : hashed level 6+xcd, full point range (L2-affine)
//   slot 2048..2303 : levels 14 AND 15 (8-way point split), x read once
//   slot 2304..2559 : dense levels 0..5  (8-way point split), x read once
__global__ __launch_bounds__(256) void level_pass(
    const float2* __restrict__ x,
    const float2* __restrict__ tbl,
    float2* __restrict__ ws)
{
    const int b    = blockIdx.x;
    const int xcd  = b & 7;         // blockIdx%8 round-robins the 8 XCDs
    const int slot = b >> 3;        // 0..2559

    if (slot < 2048) {
        const int level = 6 + xcd;  // one hashed table per XCD -> L2 hits
        const int pblk  = slot;
        const int n = (pblk << 8) | threadIdx.x;
        const float2 p = x[n];
        const float2 r = gather_level(tbl, prep_level(p, level), true);
        ws[((size_t)pblk << 12) + (level << 8) + threadIdx.x] = r;
    } else if (slot < 2304) {
        const int pblk = xcd * 256 + (slot - 2048);   // 0..2047
        const int n = (pblk << 8) | threadIdx.x;
        const float2 p = x[n];                        // x once for 2 levels
        const size_t wb = ((size_t)pblk << 12) + threadIdx.x;
#pragma unroll
        for (int level = 14; level <= 15; ++level) {
            const float2 r = gather_level(tbl, prep_level(p, level), true);
            ws[wb + (level << 8)] = r;
        }
    } else {
        const int pblk = xcd * 256 + (slot - 2304);   // 0..2047
        const int n = (pblk << 8) | threadIdx.x;
        const float2 p = x[n];                        // x once for 6 levels
        const size_t wb = ((size_t)pblk << 12) + threadIdx.x;
#pragma unroll
        for (int level = 0; level < kStartHash; ++level) {
            const float2 r = gather_level(tbl, prep_level(p, level), false);
            ws[wb + (level << 8)] = r;
        }
    }
}

// ---- Pass 2: 64-point LDS tiles, grid 8192 (at its 128-MiB BW floor) ----
static constexpr int kT2S = 66;     // stride: 4*66 mod 32 = 8 -> <=2-way (free)

__global__ __launch_bounds__(256) void transpose_out(
    const float2* __restrict__ ws,
    float4* __restrict__ out)
{
    __shared__ float2 lds[kLevels][kT2S];   // 8.4 KB

    const int t = threadIdx.x;
    const int b = blockIdx.x;               // 8192 tiles of 64 points
    const int chunk = b >> 2;               // 256-pt ws chunk
    const int coff  = (b & 3) << 6;         // 64-pt offset inside chunk
    const float2* __restrict__ base = ws + ((size_t)chunk << 12) + coff;

#pragma unroll
    for (int k = 0; k < 4; ++k) {
        const int e = (k << 8) + t;         // 0..1023 = 16 levels x 64 pts
        const int l = e >> 6;
        const int cc = e & 63;
        lds[l][cc] = base[(l << 8) + cc];   // coalesced 512-B runs per level
    }

    __syncthreads();

    float4* o = out + ((size_t)b << 9);     // 64 pts * 8 float4
#pragma unroll
    for (int k = 0; k < 2; ++k) {
        const int g  = (k << 8) + t;        // 0..511
        const int nl = g >> 3;              // local point
        const int i  = g & 7;               // float4 index in the 32-float row
        const float2 a  = lds[2 * i][nl];
        const float2 bb = lds[2 * i + 1][nl];
        nt_store4(&o[g], make_float4(a.x, a.y, bb.x, bb.y));
    }
}

// ---- Fallback: single-pass (if ws too small) ----------------------------
__global__ __launch_bounds__(256) void hashgrid_fwd(
    const float2* __restrict__ x,
    const float2* __restrict__ tbl,
    float4* __restrict__ out)
{
    const int n = blockIdx.x * blockDim.x + threadIdx.x;
    if (n >= kPoints) return;
    const float2 p = x[n];
    float acc[2 * kLevels];
#pragma unroll
    for (int l = 0; l < kLevels; ++l) {
        const float2 r = gather_level(tbl, prep_level(p, l), l >= kStartHash);
        acc[2 * l + 0] = r.x;
        acc[2 * l + 1] = r.y;
    }
    float4* o = out + (size_t)n * 8;
#pragma unroll
    for (int i = 0; i < 8; ++i)
        o[i] = make_float4(acc[4 * i + 0], acc[4 * i + 1],
                           acc[4 * i + 2], acc[4 * i + 3]);
}

extern "C" void kernel_launch(void* const* d_in, const int* in_sizes, int n_in,
                              void* d_out, int out_size, void* d_ws, size_t ws_size,
                              hipStream_t stream) {
    const float2* x   = (const float2*)d_in[0];
    const float2* tbl = (const float2*)d_in[1];

    const size_t ws_needed = (size_t)kLevels * kPoints * sizeof(float2); // 64 MiB
    if (ws_size >= ws_needed) {
        float2* ws = (float2*)d_ws;
        level_pass<<<2560 * 8, 256, 0, stream>>>(x, tbl, ws);
        transpose_out<<<kPoints / 64, 256, 0, stream>>>(ws, (float4*)d_out);
    } else {
        hashgrid_fwd<<<kPoints / 256, 256, 0, stream>>>(x, tbl, (float4*)d_out);
    }
}

// Round 10
// 197.544 us; speedup vs baseline: 1.7992x; 1.0237x over previous
//
#include <hip/hip_runtime.h>

// Multires hash-grid encode (2D, instant-NGP style). Round 13: UNMERGE 14/15.
//
// R12 counter evidence: merging levels 14+15 into one job put 8.4 MiB of
// live table per XCD L2 (2x capacity) -> thrash, FETCH 159->188 MiB, and
// the pairing win under-delivered (107.5 vs predicted 95-105). Rule locked
// in: live table working set per XCD per time window must fit 4 MiB L2.
// This round restores R11's disjoint slot ranges (disjoint time windows)
// for levels 14 and 15, keeping R12's proven wins:
//  - full pairing (dense 100% via alignment-free 16-B loads; hashed both
//    adjacency orders, ~50%) — request model verified 2 rounds running
//  - dense 0..5 merged (2.8 MiB total, L2-fits) with x read once
// Budget: pass1 ~107.5 -> ~95-100 us (22M requests @ ~13.3 req/cy/XCD-L2
// + recovered fetches), pass2 ~20 us (at its 128-MiB BW floor), harness
// overhead ~75 us fixed.

static constexpr int  kPoints    = 524288;
static constexpr int  kLevels    = 16;
static constexpr int  kStartHash = 6;
static constexpr unsigned kPs1     = 19349663u;
static constexpr unsigned kEntries = 524309u;
static constexpr unsigned kR32     = 352277u;   // 2^32 mod kEntries

typedef float v4f __attribute__((ext_vector_type(4)));

__device__ __forceinline__ void nt_store4(float4* p, const float4 v) {
    v4f t; t.x = v.x; t.y = v.y; t.z = v.z; t.w = v.w;
    __builtin_nontemporal_store(t, (v4f*)p);
}

__constant__ unsigned c_level_off[kLevels] = {
    0u, 289u, 1378u, 5603u, 22244u, 88293u, 351462u,
    875771u, 1400080u, 1924389u, 2448698u, 2973007u,
    3497316u, 4021625u, 4545934u, 5070243u
};

struct Corners {
    float    w00, w01, w10, w11;
    unsigned i00, i01, i10, i11;   // absolute table indices (level base folded in)
};

__device__ __forceinline__ Corners prep_level(const float2 p, const int l)
{
    const int   scale_i = 16 << l;
    const float scale_f = (float)scale_i;

    const float fx = p.x * scale_f;
    const float fy = p.y * scale_f;

    // coords in [0,1) -> indices nonnegative, max ~524289 at level 15: u32 ok.
    const unsigned ix0 = (unsigned)(int)fx;
    const unsigned iy0 = (unsigned)(int)fy;
    const unsigned ix1 = (unsigned)(int)(fx + 1.0f);   // NOT always ix0+1 (fp rounding)
    const unsigned iy1 = (unsigned)(int)(fy + 1.0f);

    const float ox = fx - (float)ix0;
    const float oy = fy - (float)iy0;

    const float wx1 = fminf(fmaxf(ox, 0.0f), 1.0f);
    const float wx0 = fminf(fmaxf(1.0f - ox, 0.0f), 1.0f);
    const float wy1 = fminf(fmaxf(oy, 0.0f), 1.0f);
    const float wy0 = fminf(fmaxf(1.0f - oy, 0.0f), 1.0f);

    unsigned i00, i01, i10, i11;
    if (l < kStartHash) {
        const unsigned stride = (unsigned)(scale_i + 1);
        i00 = ix0 * stride + iy0;
        i01 = ix0 * stride + iy1;
        i10 = ix1 * stride + iy0;
        i11 = ix1 * stride + iy1;
    } else {
        // 32-bit replication of ((ix ^ (iy*PS1)) % E), bit-exact vs int64:
        // hy = iy*PS1 = hi*2^32+lo, hi <= 2362, ix < 2^20 so xor touches lo only.
        // (hi*2^32 + (lo^ix)) % E = ((hi*R32)%E + (lo^ix)%E) cond-sub E.
        const unsigned long long hy0 = (unsigned long long)iy0 * kPs1;
        const unsigned long long hy1 = (unsigned long long)iy1 * kPs1;
        const unsigned lo0 = (unsigned)hy0, hi0 = (unsigned)(hy0 >> 32);
        const unsigned lo1 = (unsigned)hy1, hi1 = (unsigned)(hy1 >> 32);
        const unsigned a0 = (hi0 * kR32) % kEntries;   // hi*R32 < 2^30
        const unsigned a1 = (hi1 * kR32) % kEntries;
        i00 = a0 + ((lo0 ^ ix0) % kEntries); if (i00 >= kEntries) i00 -= kEntries;
        i01 = a1 + ((lo1 ^ ix0) % kEntries); if (i01 >= kEntries) i01 -= kEntries;
        i10 = a0 + ((lo0 ^ ix1) % kEntries); if (i10 >= kEntries) i10 -= kEntries;
        i11 = a1 + ((lo1 ^ ix1) % kEntries); if (i11 >= kEntries) i11 -= kEntries;
    }

    Corners c;
    const unsigned base = c_level_off[l];
    c.i00 = base + i00; c.i01 = base + i01;
    c.i10 = base + i10; c.i11 = base + i11;
    c.w00 = wx0 * wy0;  c.w01 = wx0 * wy1;
    c.w10 = wx1 * wy0;  c.w11 = wx1 * wy1;
    return c;
}

// Load tbl[ia], tbl[ib]. If adjacent (either order), one 16-B load at the
// lower index serves both (8-B alignment is legal for dwordx4 on gfx950;
// both covered entries are valid, so never OOB). Tested on exact indices.
__device__ __forceinline__ void load_pair(
    const float2* __restrict__ tbl, const unsigned ia, const unsigned ib,
    float2& va, float2& vb)
{
    if (ib == ia + 1u) {
        v4f q; __builtin_memcpy(&q, &tbl[ia], 16);
        va = make_float2(q.x, q.y);
        vb = make_float2(q.z, q.w);
    } else if (ia == ib + 1u) {
        v4f q; __builtin_memcpy(&q, &tbl[ib], 16);
        vb = make_float2(q.x, q.y);
        va = make_float2(q.z, q.w);
    } else {
        va = tbl[ia];
        vb = tbl[ib];
    }
}

__device__ __forceinline__ float2 gather_level(
    const float2* __restrict__ tbl, const Corners& c, const bool hashed)
{
    float2 v00, v01, v10, v11;
    if (!hashed) {
        // dense: y-neighbors adjacent ALWAYS (i01 == i00+1) -> 100% pairing
        load_pair(tbl, c.i00, c.i01, v00, v01);
        load_pair(tbl, c.i10, c.i11, v10, v11);
    } else {
        // hashed: ix0 even -> xor flips bit 0 -> i10 = i00 +/- 1 (~50%)
        load_pair(tbl, c.i00, c.i10, v00, v10);
        load_pair(tbl, c.i01, c.i11, v01, v11);
    }
    return make_float2(
        c.w00 * v00.x + c.w01 * v01.x + c.w10 * v10.x + c.w11 * v11.x,
        c.w00 * v00.y + c.w01 * v01.y + c.w10 * v10.y + c.w11 * v11.y);
}

// ---- Pass 1: XCD-affine hashed + time-separated 14/15 + merged dense ----
// Grid: 2816 slots x 8 XCDs = 22528 blocks. Disjoint slot ranges give
// disjoint time windows (blocks dispatch roughly in order), keeping the
// live table per XCD-L2 <= 4.19 MiB at all times:
//   slot    0..2047 : hashed level 6+xcd, full point range (L2-affine)
//   slot 2048..2303 : level 14 only (8-way point split)
//   slot 2304..2559 : level 15 only (8-way point split)
//   slot 2560..2815 : dense levels 0..5 merged (2.8 MiB, fits), x once
__global__ __launch_bounds__(256) void level_pass(
    const float2* __restrict__ x,
    const float2* __restrict__ tbl,
    float2* __restrict__ ws)
{
    const int b    = blockIdx.x;
    const int xcd  = b & 7;         // blockIdx%8 round-robins the 8 XCDs
    const int slot = b >> 3;        // 0..2815

    if (slot < 2048) {
        const int level = 6 + xcd;  // one hashed table per XCD -> L2 hits
        const int pblk  = slot;
        const int n = (pblk << 8) | threadIdx.x;
        const float2 p = x[n];
        const float2 r = gather_level(tbl, prep_level(p, level), true);
        ws[((size_t)pblk << 12) + (level << 8) + threadIdx.x] = r;
    } else if (slot < 2304) {
        const int pblk = xcd * 256 + (slot - 2048);   // level 14, 0..2047
        const int n = (pblk << 8) | threadIdx.x;
        const float2 p = x[n];
        const float2 r = gather_level(tbl, prep_level(p, 14), true);
        ws[((size_t)pblk << 12) + (14 << 8) + threadIdx.x] = r;
    } else if (slot < 2560) {
        const int pblk = xcd * 256 + (slot - 2304);   // level 15, 0..2047
        const int n = (pblk << 8) | threadIdx.x;
        const float2 p = x[n];
        const float2 r = gather_level(tbl, prep_level(p, 15), true);
        ws[((size_t)pblk << 12) + (15 << 8) + threadIdx.x] = r;
    } else {
        const int pblk = xcd * 256 + (slot - 2560);   // dense, 0..2047
        const int n = (pblk << 8) | threadIdx.x;
        const float2 p = x[n];                        // x once for 6 levels
        const size_t wb = ((size_t)pblk << 12) + threadIdx.x;
#pragma unroll
        for (int level = 0; level < kStartHash; ++level) {
            const float2 r = gather_level(tbl, prep_level(p, level), false);
            ws[wb + (level << 8)] = r;
        }
    }
}

// ---- Pass 2: 64-point LDS tiles, grid 8192 (at its 128-MiB BW floor) ----
static constexpr int kT2S = 66;     // stride: 4*66 mod 32 = 8 -> <=2-way (free)

__global__ __launch_bounds__(256) void transpose_out(
    const float2* __restrict__ ws,
    float4* __restrict__ out)
{
    __shared__ float2 lds[kLevels][kT2S];   // 8.4 KB

    const int t = threadIdx.x;
    const int b = blockIdx.x;               // 8192 tiles of 64 points
    const int chunk = b >> 2;               // 256-pt ws chunk
    const int coff  = (b & 3) << 6;         // 64-pt offset inside chunk
    const float2* __restrict__ base = ws + ((size_t)chunk << 12) + coff;

#pragma unroll
    for (int k = 0; k < 4; ++k) {
        const int e = (k << 8) + t;         // 0..1023 = 16 levels x 64 pts
        const int l = e >> 6;
        const int cc = e & 63;
        lds[l][cc] = base[(l << 8) + cc];   // coalesced 512-B runs per level
    }

    __syncthreads();

    float4* o = out + ((size_t)b << 9);     // 64 pts * 8 float4
#pragma unroll
    for (int k = 0; k < 2; ++k) {
        const int g  = (k << 8) + t;        // 0..511
        const int nl = g >> 3;              // local point
        const int i  = g & 7;               // float4 index in the 32-float row
        const float2 a  = lds[2 * i][nl];
        const float2 bb = lds[2 * i + 1][nl];
        nt_store4(&o[g], make_float4(a.x, a.y, bb.x, bb.y));
    }
}

// ---- Fallback: single-pass (if ws too small) ----------------------------
__global__ __launch_bounds__(256) void hashgrid_fwd(
    const float2* __restrict__ x,
    const float2* __restrict__ tbl,
    float4* __restrict__ out)
{
    const int n = blockIdx.x * blockDim.x + threadIdx.x;
    if (n >= kPoints) return;
    const float2 p = x[n];
    float acc[2 * kLevels];
#pragma unroll
    for (int l = 0; l < kLevels; ++l) {
        const float2 r = gather_level(tbl, prep_level(p, l), l >= kStartHash);
        acc[2 * l + 0] = r.x;
        acc[2 * l + 1] = r.y;
    }
    float4* o = out + (size_t)n * 8;
#pragma unroll
    for (int i = 0; i < 8; ++i)
        o[i] = make_float4(acc[4 * i + 0], acc[4 * i + 1],
                           acc[4 * i + 2], acc[4 * i + 3]);
}

extern "C" void kernel_launch(void* const* d_in, const int* in_sizes, int n_in,
                              void* d_out, int out_size, void* d_ws, size_t ws_size,
                              hipStream_t stream) {
    const float2* x   = (const float2*)d_in[0];
    const float2* tbl = (const float2*)d_in[1];

    const size_t ws_needed = (size_t)kLevels * kPoints * sizeof(float2); // 64 MiB
    if (ws_size >= ws_needed) {
        float2* ws = (float2*)d_ws;
        level_pass<<<2816 * 8, 256, 0, stream>>>(x, tbl, ws);
        transpose_out<<<kPoints / 64, 256, 0, stream>>>(ws, (float4*)d_out);
    } else {
        hashgrid_fwd<<<kPoints / 256, 256, 0, stream>>>(x, tbl, (float4*)d_out);
    }
}